// Round 6
// baseline (263.571 us; speedup 1.0000x reference)
//
#include <hip/hip_runtime.h>
#include <stdint.h>

// TopKMS (OHEM top-k MSE): per-row MSE over [N, 512] fp32, mean of top-30% rows.
// R12: R11 hit 256.5us (best ever); top-5 all fills -> every kernel <78us.
// Budget: 2 fills ~157 (fixed) + A ~72 + hist ~11 + scan ~7 + 3 gaps ~9.
// Phase A untouched (3 restructure attempts all regressed; R6 loop is proven).
// This round: fuse B1+B2 via last-block-done -- saves one dispatch + gap +
// scan cold-start (~8-12us). Coherence (G16): flush atomics device-scope;
// per-thread __threadfence() -> __syncthreads() -> t0 atomicAdd(done); last
// block re-reads hist via __hip_atomic_load(AGENT) (bypasses stale local L2)
// and scans with 256 threads (16 bins/thread). done-counter zeroed by phase A
// block 0 (stream-ordered, survives ws poison).

#define D_FEAT 512
#define NBINS 4096          // 256 bins/octave over [2^-8, 2^8)
#define HIST_SHIFT 15       // 8 mantissa bits
#define HIST_BASE (119 << 8)
#define MAIN_BLOCKS 2048
#define MAIN_THREADS 256
#define HB_BLOCKS 64
#define HB_THREADS 256

typedef float f32x4 __attribute__((ext_vector_type(4)));

// ---------------- Phase A: per-row MSE, grid-stride, NT loads ----------------
// Exact R6 structure (best measured phase A). Block 0 additionally zeroes the
// 32KB global histogram + done counter (stream-order visibility to phase B).
__global__ __launch_bounds__(MAIN_THREADS) void mse_rows_kernel(
    const float* __restrict__ input,
    const float* __restrict__ target,
    int n_rows,
    float* __restrict__ rowmse,
    int* __restrict__ g_cnt,
    float* __restrict__ g_sum,
    int* __restrict__ done_cnt)
{
    if (blockIdx.x == 0) {
        for (int i = threadIdx.x; i < NBINS; i += MAIN_THREADS) {
            g_cnt[i] = 0;
            g_sum[i] = 0.0f;
        }
        if (threadIdx.x == 0) *done_cnt = 0;
    }

    const int lane   = threadIdx.x & 63;
    const int wave   = (blockIdx.x * MAIN_THREADS + threadIdx.x) >> 6;
    const int nwaves = (MAIN_BLOCKS * MAIN_THREADS) >> 6;   // 8192
    const float inv_d = 1.0f / (float)D_FEAT;

    for (int row = wave * 2; row < n_rows; row += 2 * nwaves) {
        const int row1 = row + 1;
        const bool has1 = (row1 < n_rows);

        const f32x4* __restrict__ a0 = (const f32x4*)(input  + (size_t)row * D_FEAT);
        const f32x4* __restrict__ b0 = (const f32x4*)(target + (size_t)row * D_FEAT);
        const f32x4* __restrict__ a1 = (const f32x4*)(input  + (size_t)(has1 ? row1 : row) * D_FEAT);
        const f32x4* __restrict__ b1 = (const f32x4*)(target + (size_t)(has1 ? row1 : row) * D_FEAT);

        f32x4 A00 = __builtin_nontemporal_load(&a0[lane]);
        f32x4 A01 = __builtin_nontemporal_load(&a0[lane + 64]);
        f32x4 B00 = __builtin_nontemporal_load(&b0[lane]);
        f32x4 B01 = __builtin_nontemporal_load(&b0[lane + 64]);
        f32x4 A10 = __builtin_nontemporal_load(&a1[lane]);
        f32x4 A11 = __builtin_nontemporal_load(&a1[lane + 64]);
        f32x4 B10 = __builtin_nontemporal_load(&b1[lane]);
        f32x4 B11 = __builtin_nontemporal_load(&b1[lane + 64]);

        f32x4 d0 = A00 - B00;
        f32x4 d1 = A01 - B01;
        f32x4 d2 = A10 - B10;
        f32x4 d3 = A11 - B11;

        float acc0 = d0.x * d0.x + d0.y * d0.y + d0.z * d0.z + d0.w * d0.w
                   + d1.x * d1.x + d1.y * d1.y + d1.z * d1.z + d1.w * d1.w;
        float acc1 = d2.x * d2.x + d2.y * d2.y + d2.z * d2.z + d2.w * d2.w
                   + d3.x * d3.x + d3.y * d3.y + d3.z * d3.z + d3.w * d3.w;

        #pragma unroll
        for (int off = 32; off > 0; off >>= 1) {
            acc0 += __shfl_xor(acc0, off, 64);
            acc1 += __shfl_xor(acc1, off, 64);
        }

        if (lane == 0) {
            rowmse[row] = acc0 * inv_d;
            if (has1) rowmse[row1] = acc1 * inv_d;
        }
    }
}

// ---- Phase B (fused): LDS-privatized hist -> merge -> last block scans -----
__global__ __launch_bounds__(HB_THREADS) void hist_scan_kernel(
    const float* __restrict__ rowmse,
    int n_rows, int k,
    int* __restrict__ g_cnt,
    float* __restrict__ g_sum,
    int* __restrict__ done_cnt,
    float* __restrict__ out)
{
    __shared__ int   cnt[NBINS];
    __shared__ float sum[NBINS];
    __shared__ int   is_last;
    const int t = threadIdx.x;

    for (int i = t; i < NBINS; i += HB_THREADS) { cnt[i] = 0; sum[i] = 0.0f; }
    __syncthreads();

    const int chunk = (n_rows + HB_BLOCKS - 1) / HB_BLOCKS;   // 1024
    const int lo = blockIdx.x * chunk;
    const int hi = min(n_rows, lo + chunk);

    for (int i = lo + t; i < hi; i += HB_THREADS) {
        float v = rowmse[i];
        uint32_t bits = __float_as_uint(v);
        int bin = (int)(bits >> HIST_SHIFT) - HIST_BASE;
        bin = bin < 0 ? 0 : (bin > NBINS - 1 ? NBINS - 1 : bin);
        atomicAdd(&cnt[bin], 1);    // LDS-scope, ~1k rows/block
        atomicAdd(&sum[bin], v);
    }
    __syncthreads();

    // Flush only non-empty bins; rotate stripe order by blockIdx so different
    // blocks hit the hot bin range at different times (same-addr depth <=64).
    const int nstripes = NBINS / HB_THREADS;   // 16
    for (int s = 0; s < nstripes; ++s) {
        const int stripe = (s + blockIdx.x) & (nstripes - 1);
        const int i = stripe * HB_THREADS + t;
        int c = cnt[i];
        if (c != 0) {
            atomicAdd(&g_cnt[i], c);
            atomicAdd(&g_sum[i], sum[i]);
        }
    }

    // Release: make this block's flush globally visible, then count done.
    __threadfence();
    __syncthreads();
    if (t == 0) {
        int old = atomicAdd(done_cnt, 1);
        is_last = (old == HB_BLOCKS - 1);
    }
    __syncthreads();
    if (!is_last) return;

    // -------- Last block: scan + select with 256 threads ------------------
    __threadfence();   // acquire side
    for (int i = t; i < NBINS; i += HB_THREADS) {
        cnt[i] = __hip_atomic_load(&g_cnt[i], __ATOMIC_RELAXED,
                                   __HIP_MEMORY_SCOPE_AGENT);
        sum[i] = __hip_atomic_load(&g_sum[i], __ATOMIC_RELAXED,
                                   __HIP_MEMORY_SCOPE_AGENT);
    }
    __syncthreads();

    // descending chunks: thread t owns bins [start - ch + 1, start]
    __shared__ int   cs[HB_THREADS];
    __shared__ float ss[HB_THREADS];
    const int ch = NBINS / HB_THREADS;    // 16
    const int start = NBINS - 1 - t * ch;

    int   c_t = 0;
    float s_t = 0.0f;
    #pragma unroll
    for (int j = 0; j < ch; ++j) { c_t += cnt[start - j]; s_t += sum[start - j]; }
    cs[t] = c_t;
    ss[t] = s_t;
    __syncthreads();

    // Hillis-Steele inclusive scan over 256 threads (8 steps)
    for (int off = 1; off < HB_THREADS; off <<= 1) {
        int cv = 0; float sv = 0.0f;
        if (t >= off) { cv = cs[t - off]; sv = ss[t - off]; }
        __syncthreads();
        cs[t] += cv;
        ss[t] += sv;
        __syncthreads();
    }

    const int   c_incl   = cs[t];
    const int   c_before = c_incl - c_t;
    const float s_before = ss[t] - s_t;

    if (c_before < k && k <= c_incl) {
        int   cum = c_before;
        float s   = s_before;
        float result = 0.0f;
        for (int j = 0; j < ch; ++j) {
            int b = start - j;
            int c = cnt[b];
            if (c == 0) continue;
            if (cum + c >= k) {
                int need = k - cum;
                float avg = sum[b] / (float)c;   // bin mean, tighter than center
                result = (s + (float)need * avg) / (float)k;
                break;
            }
            cum += c;
            s   += sum[b];
        }
        out[0] = result;
    }
}

extern "C" void kernel_launch(void* const* d_in, const int* in_sizes, int n_in,
                              void* d_out, int out_size, void* d_ws, size_t ws_size,
                              hipStream_t stream)
{
    const float* input  = (const float*)d_in[0];
    const float* target = (const float*)d_in[1];
    float* out = (float*)d_out;

    const int total  = in_sizes[0];
    const int n_rows = total / D_FEAT;            // 65536
    int k = (int)(0.3 * (double)n_rows);          // matches int(K_FRAC * n)
    if (k < 1) k = 1;
    if (k > n_rows) k = n_rows;

    // Workspace layout: rowmse[n_rows] | g_cnt[NBINS] | g_sum[NBINS] | done
    float* rowmse   = (float*)d_ws;
    char*  p        = (char*)d_ws + (size_t)n_rows * sizeof(float);
    int*   g_cnt    = (int*)p;
    float* g_sum    = (float*)(p + (size_t)NBINS * sizeof(int));
    int*   done_cnt = (int*)(p + (size_t)NBINS * (sizeof(int) + sizeof(float)));

    mse_rows_kernel<<<MAIN_BLOCKS, MAIN_THREADS, 0, stream>>>(
        input, target, n_rows, rowmse, g_cnt, g_sum, done_cnt);

    hist_scan_kernel<<<HB_BLOCKS, HB_THREADS, 0, stream>>>(
        rowmse, n_rows, k, g_cnt, g_sum, done_cnt, out);
}

// Round 8
// 254.373 us; speedup vs baseline: 1.0362x; 1.0362x over previous
//
#include <hip/hip_runtime.h>
#include <stdint.h>

// TopKMS (OHEM top-k MSE): per-row MSE over [N, 512] fp32, mean of top-30% rows.
// R14: resubmit of R13 (= exact R11 composition, best measured 256.5us) --
// R13's bench was an infrastructure failure ("container failed twice"), not a
// kernel failure; this source already passed at 256.5us in round 5.
// Ledger: R11=256.5 best; all four phase-A restructures (R7/R8/R9/R10)
// regressed; fused-atomic variants (R9/R10) hit same-address serialization
// (~290us); B1+B2 fusion (R12) regressed to 263.6. Budget at 256.5: 157us
// poison fills (harness-fixed, 85% peak) + ~72us phase A (R6 loop, local
// optimum) + ~27us tail. Structural-floor candidate.
//   Phase A = exact R6 kernel (NT loads, grid-stride, 2 rows/wave, scalar
//             rowmse stores) + free block-0 hist zeroing (no memset).
//   Phase B = 64-block LDS-privatized hist (same-address depth <=64, flush
//             order rotated per block) + 32KB single-block 1024-thread scan.

#define D_FEAT 512
#define NBINS 4096          // 256 bins/octave over [2^-8, 2^8)
#define HIST_SHIFT 15       // 8 mantissa bits
#define HIST_BASE (119 << 8)
#define MAIN_BLOCKS 2048
#define MAIN_THREADS 256
#define HB_BLOCKS 64
#define HB_THREADS 256
#define SEL_THREADS 1024

typedef float f32x4 __attribute__((ext_vector_type(4)));

// ---------------- Phase A: per-row MSE, grid-stride, NT loads ----------------
// Exact R6 structure (best measured phase A). Block 0 additionally zeroes the
// 32KB global histogram (stream-order guarantees visibility to hist_kernel).
__global__ __launch_bounds__(MAIN_THREADS) void mse_rows_kernel(
    const float* __restrict__ input,
    const float* __restrict__ target,
    int n_rows,
    float* __restrict__ rowmse,
    int* __restrict__ g_cnt,
    float* __restrict__ g_sum)
{
    if (blockIdx.x == 0) {
        for (int i = threadIdx.x; i < NBINS; i += MAIN_THREADS) {
            g_cnt[i] = 0;
            g_sum[i] = 0.0f;
        }
    }

    const int lane   = threadIdx.x & 63;
    const int wave   = (blockIdx.x * MAIN_THREADS + threadIdx.x) >> 6;
    const int nwaves = (MAIN_BLOCKS * MAIN_THREADS) >> 6;   // 8192
    const float inv_d = 1.0f / (float)D_FEAT;

    for (int row = wave * 2; row < n_rows; row += 2 * nwaves) {
        const int row1 = row + 1;
        const bool has1 = (row1 < n_rows);

        const f32x4* __restrict__ a0 = (const f32x4*)(input  + (size_t)row * D_FEAT);
        const f32x4* __restrict__ b0 = (const f32x4*)(target + (size_t)row * D_FEAT);
        const f32x4* __restrict__ a1 = (const f32x4*)(input  + (size_t)(has1 ? row1 : row) * D_FEAT);
        const f32x4* __restrict__ b1 = (const f32x4*)(target + (size_t)(has1 ? row1 : row) * D_FEAT);

        f32x4 A00 = __builtin_nontemporal_load(&a0[lane]);
        f32x4 A01 = __builtin_nontemporal_load(&a0[lane + 64]);
        f32x4 B00 = __builtin_nontemporal_load(&b0[lane]);
        f32x4 B01 = __builtin_nontemporal_load(&b0[lane + 64]);
        f32x4 A10 = __builtin_nontemporal_load(&a1[lane]);
        f32x4 A11 = __builtin_nontemporal_load(&a1[lane + 64]);
        f32x4 B10 = __builtin_nontemporal_load(&b1[lane]);
        f32x4 B11 = __builtin_nontemporal_load(&b1[lane + 64]);

        f32x4 d0 = A00 - B00;
        f32x4 d1 = A01 - B01;
        f32x4 d2 = A10 - B10;
        f32x4 d3 = A11 - B11;

        float acc0 = d0.x * d0.x + d0.y * d0.y + d0.z * d0.z + d0.w * d0.w
                   + d1.x * d1.x + d1.y * d1.y + d1.z * d1.z + d1.w * d1.w;
        float acc1 = d2.x * d2.x + d2.y * d2.y + d2.z * d2.z + d2.w * d2.w
                   + d3.x * d3.x + d3.y * d3.y + d3.z * d3.z + d3.w * d3.w;

        #pragma unroll
        for (int off = 32; off > 0; off >>= 1) {
            acc0 += __shfl_xor(acc0, off, 64);
            acc1 += __shfl_xor(acc1, off, 64);
        }

        if (lane == 0) {
            rowmse[row] = acc0 * inv_d;
            if (has1) rowmse[row1] = acc1 * inv_d;
        }
    }
}

// ------- Phase B1: per-block LDS histogram -> global atomic merge -----------
// 64 blocks x 1024 rows: LDS privatization caps same-address global-atomic
// depth at 64. Flush order rotated per block to decorrelate hot-bin bursts.
__global__ __launch_bounds__(HB_THREADS) void hist_kernel(
    const float* __restrict__ rowmse,
    int n_rows,
    int* __restrict__ g_cnt,
    float* __restrict__ g_sum)
{
    __shared__ int   cnt[NBINS];
    __shared__ float sum[NBINS];
    const int t = threadIdx.x;

    for (int i = t; i < NBINS; i += HB_THREADS) { cnt[i] = 0; sum[i] = 0.0f; }
    __syncthreads();

    const int chunk = (n_rows + HB_BLOCKS - 1) / HB_BLOCKS;   // 1024
    const int lo = blockIdx.x * chunk;
    const int hi = min(n_rows, lo + chunk);

    for (int i = lo + t; i < hi; i += HB_THREADS) {
        float v = rowmse[i];
        uint32_t bits = __float_as_uint(v);
        int bin = (int)(bits >> HIST_SHIFT) - HIST_BASE;
        bin = bin < 0 ? 0 : (bin > NBINS - 1 ? NBINS - 1 : bin);
        atomicAdd(&cnt[bin], 1);    // LDS-scope, ~1k rows/block
        atomicAdd(&sum[bin], v);
    }
    __syncthreads();

    // Flush only non-empty bins; rotate stripe order by blockIdx so different
    // blocks hit the hot bin range at different times.
    const int nstripes = NBINS / HB_THREADS;   // 16
    for (int s = 0; s < nstripes; ++s) {
        const int stripe = (s + blockIdx.x) & (nstripes - 1);
        const int i = stripe * HB_THREADS + t;
        int c = cnt[i];
        if (c != 0) {
            atomicAdd(&g_cnt[i], c);
            atomicAdd(&g_sum[i], sum[i]);
        }
    }
}

// --------- Phase B2: single-block scan of the 32 KB histogram ---------------
__global__ __launch_bounds__(SEL_THREADS) void scan_select_kernel(
    const int* __restrict__ g_cnt,
    const float* __restrict__ g_sum,
    int k,
    float* __restrict__ out)
{
    __shared__ int   cnt[NBINS];
    __shared__ float sum[NBINS];
    __shared__ int   cs[SEL_THREADS];
    __shared__ float ss[SEL_THREADS];
    const int t = threadIdx.x;

    for (int i = t; i < NBINS; i += SEL_THREADS) {
        cnt[i] = g_cnt[i];
        sum[i] = g_sum[i];
    }
    __syncthreads();

    // descending chunks: thread t owns bins [start - ch + 1, start]
    const int ch = NBINS / SEL_THREADS;   // 4
    const int start = NBINS - 1 - t * ch;

    int   c_t = 0;
    float s_t = 0.0f;
    #pragma unroll
    for (int j = 0; j < ch; ++j) { c_t += cnt[start - j]; s_t += sum[start - j]; }
    cs[t] = c_t;
    ss[t] = s_t;
    __syncthreads();

    // Hillis-Steele inclusive scan (top -> bottom order)
    for (int off = 1; off < SEL_THREADS; off <<= 1) {
        int cv = 0; float sv = 0.0f;
        if (t >= off) { cv = cs[t - off]; sv = ss[t - off]; }
        __syncthreads();
        cs[t] += cv;
        ss[t] += sv;
        __syncthreads();
    }

    const int   c_incl   = cs[t];
    const int   c_before = c_incl - c_t;
    const float s_before = ss[t] - s_t;

    if (c_before < k && k <= c_incl) {
        int   cum = c_before;
        float s   = s_before;
        float result = 0.0f;
        for (int j = 0; j < ch; ++j) {
            int b = start - j;
            int c = cnt[b];
            if (c == 0) continue;
            if (cum + c >= k) {
                int need = k - cum;
                float avg = sum[b] / (float)c;   // bin mean, tighter than center
                result = (s + (float)need * avg) / (float)k;
                break;
            }
            cum += c;
            s   += sum[b];
        }
        out[0] = result;
    }
}

extern "C" void kernel_launch(void* const* d_in, const int* in_sizes, int n_in,
                              void* d_out, int out_size, void* d_ws, size_t ws_size,
                              hipStream_t stream)
{
    const float* input  = (const float*)d_in[0];
    const float* target = (const float*)d_in[1];
    float* out = (float*)d_out;

    const int total  = in_sizes[0];
    const int n_rows = total / D_FEAT;            // 65536
    int k = (int)(0.3 * (double)n_rows);          // matches int(K_FRAC * n)
    if (k < 1) k = 1;
    if (k > n_rows) k = n_rows;

    // Workspace layout: rowmse[n_rows] | g_cnt[NBINS] | g_sum[NBINS]
    float* rowmse = (float*)d_ws;
    int*   g_cnt  = (int*)((char*)d_ws + (size_t)n_rows * sizeof(float));
    float* g_sum  = (float*)((char*)d_ws + (size_t)n_rows * sizeof(float)
                                         + (size_t)NBINS * sizeof(int));

    mse_rows_kernel<<<MAIN_BLOCKS, MAIN_THREADS, 0, stream>>>(
        input, target, n_rows, rowmse, g_cnt, g_sum);

    hist_kernel<<<HB_BLOCKS, HB_THREADS, 0, stream>>>(rowmse, n_rows, g_cnt, g_sum);

    scan_select_kernel<<<1, SEL_THREADS, 0, stream>>>(g_cnt, g_sum, k, out);
}